// Round 3
// baseline (74.113 us; speedup 1.0000x reference)
//
#include <hip/hip_runtime.h>

// out[b,o] = sum_j sum_d coeff[o*128+j, d] * x[b,j]^d
// == GEMM: out[M=8192, N=128] = P[M,K=512] * W[N,K=512]^T
//   k = j*4+d; W = coeff viewed as [128, 512] row-major;
//   P[b,k] = x[b, k>>2]^(k&3), built in-register per MFMA fragment.
//
// Single dispatch (per-dispatch overhead is first-order at this size: the
// R2 prep-kernel split cost +7 us). Zero LDS, zero barriers: each wave owns
// a 16Mx32N output tile, gathers A/B fragments directly from global, and
// converts W fp32->bf16 in-register per fragment (4 v_cvt_pk per frag).
// K=512 fully unrolled as 16 mfma_f32_16x16x32_bf16 steps x 2 N-chains.

#define BATCH   8192
#define IN_DIM  128
#define OUT_DIM 128
#define KDIM    512

typedef __attribute__((ext_vector_type(8))) short bf16x8;
typedef __attribute__((ext_vector_type(4))) float f32x4;

__device__ inline unsigned short f2bf(float f) {
    union { float f; unsigned int u; } v; v.f = f;
    unsigned int u = v.u;
    u += 0x7FFFu + ((u >> 16) & 1u);   // round-to-nearest-even
    return (unsigned short)(u >> 16);
}

#if defined(__has_builtin)
#if __has_builtin(__builtin_amdgcn_cvt_pk_bf16_f32)
#define HAVE_HW_PKBF16 1
#endif
#endif

#ifdef HAVE_HW_PKBF16
typedef __attribute__((ext_vector_type(2))) __bf16 bf16x2_t;
__device__ inline unsigned int pk2(float a, float b) {
    bf16x2_t r = __builtin_amdgcn_cvt_pk_bf16_f32(a, b);
    union { bf16x2_t v; unsigned int u; } c; c.v = r; return c.u;
}
#else
__device__ inline unsigned int pk2(float a, float b) {
    return (unsigned int)f2bf(a) | ((unsigned int)f2bf(b) << 16);
}
#endif

union frag_u { unsigned int u[4]; bf16x8 v; };

__device__ inline bf16x8 cvt_frag(const float4 a, const float4 b) {
    frag_u f;
    f.u[0] = pk2(a.x, a.y);
    f.u[1] = pk2(a.z, a.w);
    f.u[2] = pk2(b.x, b.y);
    f.u[3] = pk2(b.z, b.w);
    return f.v;
}

__global__ __launch_bounds__(64) void kan_mfma(const float* __restrict__ x,
                                               const float* __restrict__ coeff,
                                               float* __restrict__ out) {
    const int lane = threadIdx.x;       // 0..63
    const int q    = lane >> 4;         // quad 0..3
    const int r    = lane & 15;
    const int m0   = blockIdx.x * 16;
    const int n0   = blockIdx.y * 32;

    const float* xrow  = x     + (size_t)(m0 + r) * IN_DIM;       // A row (shared by both chains)
    const float* w0row = coeff + (size_t)(n0 + r) * KDIM;         // B rows, chain 0
    const float* w1row = coeff + (size_t)(n0 + 16 + r) * KDIM;    // B rows, chain 1

    f32x4 acc0 = {0.f, 0.f, 0.f, 0.f};
    f32x4 acc1 = {0.f, 0.f, 0.f, 0.f};

    #pragma unroll
    for (int s = 0; s < KDIM / 32; ++s) {           // 16 k-steps of 32
        const int ko = s * 32 + q * 8;
        // B fragments: 8 fp32 each, converted in-register (RNE)
        const float4 b0a = *(const float4*)(w0row + ko);
        const float4 b0b = *(const float4*)(w0row + ko + 4);
        const float4 b1a = *(const float4*)(w1row + ko);
        const float4 b1b = *(const float4*)(w1row + ko + 4);

        // A fragment: powers {1,x0,x0^2,x0^3, 1,x1,x1^2,x1^3} of two x values
        const float2 xv = *(const float2*)(xrow + s * 8 + q * 2);
        const float x0 = xv.x, x1 = xv.y;
        frag_u af;
        af.u[0] = pk2(1.0f, x0);
        af.u[1] = pk2(x0 * x0, x0 * x0 * x0);
        af.u[2] = pk2(1.0f, x1);
        af.u[3] = pk2(x1 * x1, x1 * x1 * x1);

        const bf16x8 bf0 = cvt_frag(b0a, b0b);
        const bf16x8 bf1 = cvt_frag(b1a, b1b);

        acc0 = __builtin_amdgcn_mfma_f32_16x16x32_bf16(af.v, bf0, acc0, 0, 0, 0);
        acc1 = __builtin_amdgcn_mfma_f32_16x16x32_bf16(af.v, bf1, acc1, 0, 0, 0);
    }

    // C/D layout: col = lane&15, row = quad*4 + reg
    float* orow = out + (size_t)(m0 + q * 4) * OUT_DIM + n0 + r;
    #pragma unroll
    for (int rr = 0; rr < 4; ++rr) {
        orow[rr * OUT_DIM]      = acc0[rr];
        orow[rr * OUT_DIM + 16] = acc1[rr];
    }
}

extern "C" void kernel_launch(void* const* d_in, const int* in_sizes, int n_in,
                              void* d_out, int out_size, void* d_ws, size_t ws_size,
                              hipStream_t stream) {
    const float* x     = (const float*)d_in[0];   // [8192, 128] fp32
    const float* coeff = (const float*)d_in[1];   // [16384, 4] fp32 == [128, 512]
    float* out = (float*)d_out;                   // [8192, 128] fp32

    dim3 grid(BATCH / 16, OUT_DIM / 32);          // 512 x 4 = 2048 waves, 8 waves/CU
    kan_mfma<<<grid, 64, 0, stream>>>(x, coeff, out);
}

// Round 4
// 61.547 us; speedup vs baseline: 1.2042x; 1.2042x over previous
//
#include <hip/hip_runtime.h>

// out[b,o] = sum_j sum_d coeff[o*128+j, d] * x[b,j]^d
// == GEMM: out[M=8192, N=128] = P[M,K=512] * W[N,K=512]^T
//   k = j*4+d; W = coeff viewed as [128, 512] row-major;
//   P[b,k] = x[b, k>>2]^(k&3), computed during LDS staging.
//
// R3 lesson: direct per-lane fragment gathers are L1-bound (16 cache lines
// per load instr). Back to coalesced-load + LDS-distribute (R1 structure),
// with fixed barrier economics:
//  - W staged to LDS ONCE per block (bf16, 33 KB) -> no W work in K-loop
//  - x-powers tile double-buffered, write-to-other-buffer -> 1 barrier/stage
//  - 4 stages (BK=128) x 4 k-steps x 2 chains = 32 MFMAs per barrier
// Block 256 thr = 4 waves, tile 64Mx32N (wave: 16Mx32N). LDS 68 KB -> 2
// blocks/CU. Grid (128,4) = 512 blocks.

#define BATCH   8192
#define IN_DIM  128
#define OUT_DIM 128
#define KDIM    512
#define M_BLK   64
#define N_BLK   32
#define BK      128            // k per stage (32 j-columns)
#define NSTAGE  (KDIM / BK)    // 4
#define WPAD    520            // W row stride, bf16 units (512 + 8)
#define APAD    136            // A row stride, bf16 units (128 + 8)

typedef __attribute__((ext_vector_type(8))) short bf16x8;
typedef __attribute__((ext_vector_type(4))) float f32x4;

__device__ inline unsigned short f2bf(float f) {
    union { float f; unsigned int u; } v; v.f = f;
    unsigned int u = v.u;
    u += 0x7FFFu + ((u >> 16) & 1u);   // round-to-nearest-even
    return (unsigned short)(u >> 16);
}

#if defined(__has_builtin)
#if __has_builtin(__builtin_amdgcn_cvt_pk_bf16_f32)
#define HAVE_HW_PKBF16 1
#endif
#endif

#ifdef HAVE_HW_PKBF16
typedef __attribute__((ext_vector_type(2))) __bf16 bf16x2_t;
__device__ inline unsigned int pk2(float a, float b) {
    bf16x2_t r = __builtin_amdgcn_cvt_pk_bf16_f32(a, b);
    union { bf16x2_t v; unsigned int u; } c; c.v = r; return c.u;
}
#else
__device__ inline unsigned int pk2(float a, float b) {
    return (unsigned int)f2bf(a) | ((unsigned int)f2bf(b) << 16);
}
#endif

// 4 x-values -> 16 bf16 powers {1,x,x^2,x^3} each, two 16B LDS writes
__device__ inline void write_pow4(unsigned short* dst, const float4 v) {
    unsigned int o[8];
    o[0] = pk2(1.0f, v.x); o[1] = pk2(v.x * v.x, v.x * v.x * v.x);
    o[2] = pk2(1.0f, v.y); o[3] = pk2(v.y * v.y, v.y * v.y * v.y);
    o[4] = pk2(1.0f, v.z); o[5] = pk2(v.z * v.z, v.z * v.z * v.z);
    o[6] = pk2(1.0f, v.w); o[7] = pk2(v.w * v.w, v.w * v.w * v.w);
    *(uint4*)(dst)     = *(uint4*)&o[0];
    *(uint4*)(dst + 8) = *(uint4*)&o[4];
}

__global__ __launch_bounds__(256) void kan_mfma(const float* __restrict__ x,
                                                const float* __restrict__ coeff,
                                                float* __restrict__ out) {
    __shared__ __align__(16) unsigned short W_lds[N_BLK * WPAD];       // 33.3 KB
    __shared__ __align__(16) unsigned short A_lds[2][M_BLK * APAD];    // 34.8 KB

    const int t    = threadIdx.x;
    const int w    = t >> 6;          // wave 0..3 -> M sub-tile
    const int lane = t & 63;
    const int q    = lane >> 4;
    const int r    = lane & 15;
    const int m0   = blockIdx.x * M_BLK;
    const int n0   = blockIdx.y * N_BLK;

    // ---- W staging (once): 32 rows x 512 f32 -> bf16 LDS, fully coalesced ----
    #pragma unroll
    for (int i = 0; i < 16; ++i) {
        const int f    = i * 256 + t;        // float4 index, 0..4095
        const int row  = f >> 7;             // 128 float4 per row
        const int col4 = f & 127;
        const float4 c = *(const float4*)&coeff[(size_t)(n0 + row) * KDIM + col4 * 4];
        uint2 o;
        o.x = pk2(c.x, c.y);
        o.y = pk2(c.z, c.w);
        *(uint2*)&W_lds[row * WPAD + col4 * 4] = o;
    }

    // x chunk staging map: 512 float4 per chunk, thread covers f = t, t+256
    const int xr0 = t >> 3;                  // rows 0..31
    const int xr1 = (t + 256) >> 3;          // rows 32..63
    const int xc4 = t & 7;                   // float4 col within 32-j chunk

    // ---- chunk 0 -> buf 0 ----
    float4 p0 = *(const float4*)&x[(size_t)(m0 + xr0) * IN_DIM + xc4 * 4];
    float4 p1 = *(const float4*)&x[(size_t)(m0 + xr1) * IN_DIM + xc4 * 4];
    write_pow4(&A_lds[0][xr0 * APAD + xc4 * 16], p0);
    write_pow4(&A_lds[0][xr1 * APAD + xc4 * 16], p1);
    __syncthreads();

    f32x4 acc0 = {0.f, 0.f, 0.f, 0.f};
    f32x4 acc1 = {0.f, 0.f, 0.f, 0.f};

    for (int s = 0; s < NSTAGE; ++s) {
        // prefetch next x chunk while computing on current buffer
        if (s + 1 < NSTAGE) {
            const int jc = (s + 1) * 32;
            p0 = *(const float4*)&x[(size_t)(m0 + xr0) * IN_DIM + jc + xc4 * 4];
            p1 = *(const float4*)&x[(size_t)(m0 + xr1) * IN_DIM + jc + xc4 * 4];
        }

        const unsigned short* Ab = A_lds[s & 1];
        #pragma unroll
        for (int u = 0; u < BK / 32; ++u) {     // 4 k-steps
            const int ko = u * 32 + q * 8;
            const bf16x8 av = *(const bf16x8*)&Ab[(w * 16 + r) * APAD + ko];
            const bf16x8 b0 = *(const bf16x8*)&W_lds[r        * WPAD + s * BK + ko];
            const bf16x8 b1 = *(const bf16x8*)&W_lds[(16 + r) * WPAD + s * BK + ko];
            acc0 = __builtin_amdgcn_mfma_f32_16x16x32_bf16(av, b0, acc0, 0, 0, 0);
            acc1 = __builtin_amdgcn_mfma_f32_16x16x32_bf16(av, b1, acc1, 0, 0, 0);
        }

        if (s + 1 < NSTAGE) {
            // write OTHER buffer; single barrier covers write->read ordering
            unsigned short* An = A_lds[(s + 1) & 1];
            write_pow4(&An[xr0 * APAD + xc4 * 16], p0);
            write_pow4(&An[xr1 * APAD + xc4 * 16], p1);
            __syncthreads();
        }
    }

    // ---- epilogue: C/D layout col = lane&15, row = quad*4 + reg ----
    float* obase = out + (size_t)(m0 + w * 16 + q * 4) * OUT_DIM + n0 + r;
    #pragma unroll
    for (int rr = 0; rr < 4; ++rr) {
        obase[rr * OUT_DIM]      = acc0[rr];
        obase[rr * OUT_DIM + 16] = acc1[rr];
    }
}

extern "C" void kernel_launch(void* const* d_in, const int* in_sizes, int n_in,
                              void* d_out, int out_size, void* d_ws, size_t ws_size,
                              hipStream_t stream) {
    const float* x     = (const float*)d_in[0];   // [8192, 128] fp32
    const float* coeff = (const float*)d_in[1];   // [16384, 4] fp32 == [128, 512]
    float* out = (float*)d_out;                   // [8192, 128] fp32

    dim3 grid(BATCH / M_BLK, OUT_DIM / N_BLK);    // 128 x 4 = 512 blocks
    kan_mfma<<<grid, 256, 0, stream>>>(x, coeff, out);
}